// Round 2
// baseline (267.060 us; speedup 1.0000x reference)
//
#include <hip/hip_runtime.h>
#include <hip/hip_bf16.h>

#define NB 8
#define NC 128
#define NN 2048
#define NH 4
#define HD 32
#define NOUT 128
#define QB 16

typedef _Float16 half8 __attribute__((ext_vector_type(8)));
typedef _Float16 half4 __attribute__((ext_vector_type(4)));
typedef float f32x4 __attribute__((ext_vector_type(4)));

__device__ __forceinline__ f32x4 mfma16(half8 a, half8 b, f32x4 c) {
  return __builtin_amdgcn_mfma_f32_16x16x32_f16(a, b, c, 0, 0, 0);
}

// ---------------- Kernel 0: weight prep (fp32 -> fp16, transposed) ----------------
// WqT/WkT/WvT: [H][HD][C] from W[H][C][HD]; WoT: [o][c] from Wo[c][o].
__global__ __launch_bounds__(256) void k_prep(
    const float* __restrict__ Wq, const float* __restrict__ Wk,
    const float* __restrict__ Wv, const float* __restrict__ Wo,
    _Float16* __restrict__ WqT, _Float16* __restrict__ WkT,
    _Float16* __restrict__ WvT, _Float16* __restrict__ WoT)
{
  int id = blockIdx.x * 256 + threadIdx.x;       // 65536 total
  if (id < 3 * 16384) {
    int m = id >> 14, rem = id & 16383;
    int h = rem >> 12, d = (rem >> 7) & 31, c = rem & 127;
    const float* W = (m == 0) ? Wq : (m == 1) ? Wk : Wv;
    _Float16* WT   = (m == 0) ? WqT : (m == 1) ? WkT : WvT;
    WT[(h * 32 + d) * 128 + c] = (_Float16)W[(h * 128 + c) * 32 + d];
  } else {
    int j = id - 49152;
    int o = j >> 7, c = j & 127;
    WoT[o * 128 + c] = (_Float16)Wo[c * 128 + o];
  }
}

// ---------------- Kernel 1: QKV projections ----------------
// grid 512 (b = bid&7, n0 = (bid>>3)*32), 256 threads, wave = head.
__global__ __launch_bounds__(256) void k_proj(
    const float* __restrict__ x, const _Float16* __restrict__ WqT,
    const _Float16* __restrict__ WkT, const _Float16* __restrict__ WvT,
    _Float16* __restrict__ qo, _Float16* __restrict__ ko, _Float16* __restrict__ vto)
{
  __shared__ _Float16 xs[32][136];   // [n][C], +8 pad
  const int bid = blockIdx.x;
  const int b  = bid & 7;
  const int n0 = (bid >> 3) * 32;
  const int tid = threadIdx.x;
  const int h = tid >> 6, l = tid & 63, lr = l & 15, lg = l >> 4;

  // stage x[b][:, n0:n0+32) transposed -> xs[n][c] fp16 (vector global loads)
  {
    int c  = tid >> 1;
    int nq = (tid & 1) * 16;
    const float* src = x + (size_t)(b * NC + c) * NN + n0 + nq;
#pragma unroll
    for (int i = 0; i < 4; ++i) {
      f32x4 v = *(const f32x4*)(src + i * 4);
#pragma unroll
      for (int j = 0; j < 4; ++j) xs[nq + i * 4 + j][c] = (_Float16)v[j];
    }
  }
  __syncthreads();

  half8 a[2][4];
#pragma unroll
  for (int rf = 0; rf < 2; ++rf)
#pragma unroll
    for (int kc = 0; kc < 4; ++kc)
      a[rf][kc] = *(const half8*)(&xs[rf * 16 + lr][kc * 32 + lg * 8]);

#pragma unroll
  for (int m = 0; m < 2; ++m) {
    const _Float16* WT = m ? WkT : WqT;
    _Float16* dst      = m ? ko : qo;
    f32x4 acc[2][2] = {};
#pragma unroll
    for (int kc = 0; kc < 4; ++kc) {
      half8 wb[2];
#pragma unroll
      for (int cf = 0; cf < 2; ++cf)
        wb[cf] = *(const half8*)(WT + (size_t)(h * HD + cf * 16 + lr) * NC + kc * 32 + lg * 8);
#pragma unroll
      for (int rf = 0; rf < 2; ++rf)
#pragma unroll
        for (int cf = 0; cf < 2; ++cf)
          acc[rf][cf] = mfma16(a[rf][kc], wb[cf], acc[rf][cf]);
    }
#pragma unroll
    for (int rf = 0; rf < 2; ++rf)
#pragma unroll
      for (int cf = 0; cf < 2; ++cf)
#pragma unroll
        for (int r = 0; r < 4; ++r)
          dst[((size_t)(b * NH + h) * NN + n0 + rf * 16 + lg * 4 + r) * HD + cf * 16 + lr] =
              (_Float16)acc[rf][cf][r];
  }

  // vT = Wv^T · x -> vto[b][h][d][n]
  {
    f32x4 acc[2][2] = {};
#pragma unroll
    for (int kc = 0; kc < 4; ++kc) {
      half8 aw[2];
#pragma unroll
      for (int rf = 0; rf < 2; ++rf)
        aw[rf] = *(const half8*)(WvT + (size_t)(h * HD + rf * 16 + lr) * NC + kc * 32 + lg * 8);
#pragma unroll
      for (int rf = 0; rf < 2; ++rf)
#pragma unroll
        for (int nf = 0; nf < 2; ++nf)
          acc[rf][nf] = mfma16(aw[rf], a[nf][kc], acc[rf][nf]);
    }
#pragma unroll
    for (int rf = 0; rf < 2; ++rf)
#pragma unroll
      for (int nf = 0; nf < 2; ++nf)
#pragma unroll
        for (int r = 0; r < 4; ++r)
          vto[((size_t)(b * NH + h) * HD + rf * 16 + lg * 4 + r) * NN + n0 + nf * 16 + lr] =
              (_Float16)acc[rf][nf][r];
  }
}

// ---------------- Kernel 2: attention + adj + W_o ----------------
union SMem {
  _Float16 p[NH * QB * 72];                                  // 9216 B
  struct { _Float16 ocat[QB * 136]; float ot[128 * 20]; } ep; // 4352 + 10240 B
};

__global__ __launch_bounds__(256) void k_attn(
    const _Float16* __restrict__ q, const _Float16* __restrict__ k,
    const _Float16* __restrict__ vt, const _Float16* __restrict__ WoT,
    float* __restrict__ outT, float* __restrict__ adj)
{
  __shared__ SMem sm;
  const int bid = blockIdx.x;
  const int b  = bid & 7;                 // batch == XCD -> K/V L2-resident
  const int n0 = (bid >> 3) * QB;
  const int h  = threadIdx.x >> 6;
  const int l  = threadIdx.x & 63;
  const int lr = l & 15, lg = l >> 4;

  const _Float16* qh = q  + (size_t)(b * NH + h) * NN * HD;
  const _Float16* kh = k  + (size_t)(b * NH + h) * NN * HD;
  const _Float16* vh = vt + (size_t)(b * NH + h) * HD * NN;

  half8 qa = *(const half8*)(qh + (size_t)(n0 + lr) * HD + lg * 8);

  const float c1 = 0.25504527f;   // (1/sqrt(32)) * log2(e)
  const float c2 = 17.3123405f;   // 12 * log2(e)

  // ---- Pass 1: row sums (2 independent chains per iter for ILP) ----
  float rs[4] = {};
  for (int mt = 0; mt < NN / 32; ++mt) {
    half8 kb0 = *(const half8*)(kh + (size_t)(mt * 32 + lr) * HD + lg * 8);
    half8 kb1 = *(const half8*)(kh + (size_t)(mt * 32 + 16 + lr) * HD + lg * 8);
    f32x4 z{};
    f32x4 s0 = mfma16(qa, kb0, z);
    f32x4 s1 = mfma16(qa, kb1, z);
#pragma unroll
    for (int r = 0; r < 4; ++r)
      rs[r] += __builtin_amdgcn_exp2f(s0[r] * c1 - c2) +
               __builtin_amdgcn_exp2f(s1[r] * c1 - c2);
  }
#pragma unroll
  for (int r = 0; r < 4; ++r) {
    float v = rs[r];
    v += __shfl_xor(v, 1); v += __shfl_xor(v, 2);
    v += __shfl_xor(v, 4); v += __shfl_xor(v, 8);
    rs[r] = 1.0f / v;
  }

  // ---- Pass 2: p -> LDS, PV MFMA, adj head-mean write ----
  f32x4 oacc[2] = {};
  const int tr = threadIdx.x >> 4;         // 0..15
  const int tc = (threadIdx.x & 15) * 4;   // 0..60

  for (int mt2 = 0; mt2 < NN / 64; ++mt2) {
#pragma unroll
    for (int st = 0; st < 4; ++st) {
      half8 kb = *(const half8*)(kh + (size_t)(mt2 * 64 + st * 16 + lr) * HD + lg * 8);
      f32x4 z{};
      f32x4 s = mfma16(qa, kb, z);
#pragma unroll
      for (int r = 0; r < 4; ++r)
        sm.p[(h * QB + lg * 4 + r) * 72 + st * 16 + lr] =
            (_Float16)(__builtin_amdgcn_exp2f(s[r] * c1 - c2) * rs[r]);
    }
    __syncthreads();
#pragma unroll
    for (int kc = 0; kc < 2; ++kc) {
      half8 pa  = *(const half8*)(&sm.p[(h * QB + lr) * 72 + kc * 32 + lg * 8]);
      half8 vb0 = *(const half8*)(vh + (size_t)lr * NN        + mt2 * 64 + kc * 32 + lg * 8);
      half8 vb1 = *(const half8*)(vh + (size_t)(16 + lr) * NN + mt2 * 64 + kc * 32 + lg * 8);
      oacc[0] = mfma16(pa, vb0, oacc[0]);
      oacc[1] = mfma16(pa, vb1, oacc[1]);
    }
    {
      float a4[4] = {};
#pragma unroll
      for (int h2 = 0; h2 < 4; ++h2) {
        half4 pv = *(const half4*)(&sm.p[(h2 * QB + tr) * 72 + tc]);
#pragma unroll
        for (int i = 0; i < 4; ++i) a4[i] += (float)pv[i];
      }
      f32x4 w = {a4[0] * 0.25f, a4[1] * 0.25f, a4[2] * 0.25f, a4[3] * 0.25f};
      *(f32x4*)(adj + ((size_t)(b * NN) + n0 + tr) * NN + mt2 * 64 + tc) = w;
    }
    __syncthreads();
  }

  // ---- Epilogue: concat heads -> W_o -> transposed coalesced store ----
#pragma unroll
  for (int df = 0; df < 2; ++df)
#pragma unroll
    for (int r = 0; r < 4; ++r)
      sm.ep.ocat[(lg * 4 + r) * 136 + h * 32 + df * 16 + lr] = (_Float16)oacc[df][r];
  __syncthreads();

  f32x4 o2[2] = {};
#pragma unroll
  for (int kc = 0; kc < 4; ++kc) {
    half8 a2 = *(const half8*)(&sm.ep.ocat[lr * 136 + kc * 32 + lg * 8]);
#pragma unroll
    for (int of = 0; of < 2; ++of) {
      half8 wb = *(const half8*)(WoT + (size_t)(h * 32 + of * 16 + lr) * NOUT + kc * 32 + lg * 8);
      o2[of] = mfma16(a2, wb, o2[of]);
    }
  }
#pragma unroll
  for (int of = 0; of < 2; ++of)
#pragma unroll
    for (int r = 0; r < 4; ++r)
      sm.ep.ot[(h * 32 + of * 16 + lr) * 20 + lg * 4 + r] = o2[of][r];
  __syncthreads();
  {
    int o  = threadIdx.x >> 1;
    int hf = threadIdx.x & 1;
    float* dst = outT + ((size_t)(b * NOUT) + o) * NN + n0 + hf * 8;
    *(f32x4*)(dst)     = *(const f32x4*)(&sm.ep.ot[o * 20 + hf * 8]);
    *(f32x4*)(dst + 4) = *(const f32x4*)(&sm.ep.ot[o * 20 + hf * 8 + 4]);
  }
}

extern "C" void kernel_launch(void* const* d_in, const int* in_sizes, int n_in,
                              void* d_out, int out_size, void* d_ws, size_t ws_size,
                              hipStream_t stream) {
  const float* x  = (const float*)d_in[0];
  const float* Wq = (const float*)d_in[1];
  const float* Wk = (const float*)d_in[2];
  const float* Wv = (const float*)d_in[3];
  const float* Wo = (const float*)d_in[4];

  float* outT = (float*)d_out;                   // [B,128,N]
  float* adj  = outT + (size_t)NB * NOUT * NN;   // [B,N,N]

  const size_t qkv_elems = (size_t)NB * NH * NN * HD;   // 2,097,152 each
  _Float16* qw  = (_Float16*)d_ws;
  _Float16* kw  = qw + qkv_elems;
  _Float16* vw  = kw + qkv_elems;
  _Float16* wqT = vw + qkv_elems;
  _Float16* wkT = wqT + 16384;
  _Float16* wvT = wkT + 16384;
  _Float16* woT = wvT + 16384;

  k_prep<<<dim3(256), dim3(256), 0, stream>>>(Wq, Wk, Wv, Wo, wqT, wkT, wvT, woT);
  k_proj<<<dim3(NB * (NN / 32)), dim3(256), 0, stream>>>(x, wqT, wkT, wvT, qw, kw, vw);
  k_attn<<<dim3(NB * (NN / QB)), dim3(256), 0, stream>>>(qw, kw, vw, woT, outT, adj);
}